// Round 10
// baseline (289.671 us; speedup 1.0000x reference)
//
#include <hip/hip_runtime.h>
#include <math.h>

#define BTOT 131072
#define NBK 3
#define SS 16
#define NA 9
#define BAD 25      // SS+NA
#define STR 28      // padded row stride in the fp32 weight image
#define VD 128
#define CM 10
#define OUTD 51     // NBK*SS + 3
#define EPS 1e-8f
#define EPB 128     // elements per block (2 threads each)

// ---- fp32 folded-weight image (float offsets in ws) ----
#define O_GQK  0        // 25 x 28  full Wq^T Wk
#define O_GQQ  700      // 25 x 28  lower-tri (off-diag x2) of Wq^T Wq
#define O_GKK  1400     // 25 x 28  lower-tri (off-diag x2) of Wk^T Wk
#define O_V1   2100     // 28: Wq^T bk
#define O_V2   2128     // 28: Wk^T bq
#define O_VQ   2156     // 28: Wq^T bq
#define O_VK   2184     // 28: Wk^T bk
#define O_C    2212     // c0, cq, ck, pad
#define O_M    2216     // 128 x 28 fp32 (kept for layout)
#define O_MB   5800     // 128
#define O_W2T  5928     // 128 x 16
#define O_B2   7976     // 16
#define O_WC1  7992     // 10 x 84
#define O_BC1  8832     // 12
#define O_WC2  8844     // 3 x 12
#define O_BC2  8880     // 4
#define LDS_F  8884
// ---- bf16 MFMA-packed B-fragments ----
#define O_PKM  LDS_F
#define O_PKW2 (LDS_F + 2048)
#define PKM_N  4096
#define PKW2_N 2048
#define TOT_IDX (LDS_F + PKM_N + PKW2_N)

typedef __attribute__((ext_vector_type(8))) short short8;
typedef __attribute__((ext_vector_type(4))) float floatx4;

__device__ __forceinline__ float fast_sigmoid(float x) {
    return __builtin_amdgcn_rcpf(1.0f + __expf(-x));
}

__device__ __forceinline__ unsigned short f2bf(float f) {
    unsigned int u = __float_as_uint(f);
    u += 0x7FFFu + ((u >> 16) & 1u);   // round-to-nearest-even
    return (unsigned short)(u >> 16);
}

__global__ void prep_kernel(const float* __restrict__ Wq, const float* __restrict__ bq,
                            const float* __restrict__ Wk, const float* __restrict__ bk,
                            const float* __restrict__ Wv, const float* __restrict__ bv,
                            const float* __restrict__ W1, const float* __restrict__ b1,
                            const float* __restrict__ W2, const float* __restrict__ b2,
                            const float* __restrict__ Wc1, const float* __restrict__ bc1,
                            const float* __restrict__ Wc2, const float* __restrict__ bc2,
                            float* __restrict__ ws) {
    int idx = blockIdx.x * 256 + threadIdx.x;
    if (idx >= TOT_IDX) return;

    if (idx >= LDS_F) {
        int p = idx - LDS_F;
        if (p < PKM_N) {
            int tile = p >> 9, lane = (p >> 3) & 63, j = p & 7;
            int n = tile * 16 + (lane & 15);
            int k = ((lane >> 4) << 3) + j;
            float val = 0.0f;
            if (k < BAD) {
                float s = 0.f;
                for (int c = 0; c < VD; ++c) s += W1[n * VD + c] * Wv[c * BAD + k];
                val = 2.0f * s;
            } else if (k == BAD) {
                float s = b1[n];
                for (int c = 0; c < VD; ++c) s += W1[n * VD + c] * bv[c];
                val = 2.0f * s;
            }
            ((unsigned short*)(ws + O_PKM))[p] = f2bf(val);
        } else {
            int q2 = p - PKM_N;
            int kt = q2 >> 9, lane = (q2 >> 3) & 63, j = q2 & 7;
            int o = lane & 15;
            int k = kt * 32 + ((lane >> 4) << 3) + j;
            ((unsigned short*)(ws + O_PKW2))[q2] = f2bf(W2[o * VD + k]);
        }
        return;
    }

    float val = 0.0f;
    if (idx < O_GQQ) {
        int e = idx / STR, f = idx % STR;
        if (f < BAD) {
            float s = 0.f;
            for (int d = 0; d < VD; ++d) s += Wq[d * BAD + e] * Wk[d * BAD + f];
            val = s;
        }
    } else if (idx < O_GKK) {
        int j = idx - O_GQQ; int e = j / STR, f = j % STR;
        if (f < BAD && f <= e) {
            float s = 0.f;
            for (int d = 0; d < VD; ++d) s += Wq[d * BAD + e] * Wq[d * BAD + f];
            val = (f == e) ? s : 2.0f * s;
        }
    } else if (idx < O_V1) {
        int j = idx - O_GKK; int e = j / STR, f = j % STR;
        if (f < BAD && f <= e) {
            float s = 0.f;
            for (int d = 0; d < VD; ++d) s += Wk[d * BAD + e] * Wk[d * BAD + f];
            val = (f == e) ? s : 2.0f * s;
        }
    } else if (idx < O_V2) {
        int e = idx - O_V1;
        if (e < BAD) { float s = 0.f; for (int d = 0; d < VD; ++d) s += Wq[d * BAD + e] * bk[d]; val = s; }
    } else if (idx < O_VQ) {
        int e = idx - O_V2;
        if (e < BAD) { float s = 0.f; for (int d = 0; d < VD; ++d) s += Wk[d * BAD + e] * bq[d]; val = s; }
    } else if (idx < O_VK) {
        int e = idx - O_VQ;
        if (e < BAD) { float s = 0.f; for (int d = 0; d < VD; ++d) s += Wq[d * BAD + e] * bq[d]; val = s; }
    } else if (idx < O_C) {
        int e = idx - O_VK;
        if (e < BAD) { float s = 0.f; for (int d = 0; d < VD; ++d) s += Wk[d * BAD + e] * bk[d]; val = s; }
    } else if (idx < O_M) {
        int j = idx - O_C;
        if (j == 0) { float s = 0.f; for (int d = 0; d < VD; ++d) s += bq[d] * bk[d]; val = s; }
        else if (j == 1) { float s = 0.f; for (int d = 0; d < VD; ++d) s += bq[d] * bq[d]; val = s; }
        else if (j == 2) { float s = 0.f; for (int d = 0; d < VD; ++d) s += bk[d] * bk[d]; val = s; }
    } else if (idx < O_MB) {
        int j = idx - O_M; int r = j / STR, c = j % STR;
        if (c < BAD) {
            float s = 0.f;
            for (int k = 0; k < VD; ++k) s += W1[r * VD + k] * Wv[k * BAD + c];
            val = 2.0f * s;
        }
    } else if (idx < O_W2T) {
        int d = idx - O_MB;
        float s = b1[d];
        for (int k = 0; k < VD; ++k) s += W1[d * VD + k] * bv[k];
        val = 2.0f * s;
    } else if (idx < O_B2) {
        int j = idx - O_W2T; int d = j / 16, o = j % 16;
        val = W2[o * VD + d];
    } else if (idx < O_WC1) {
        val = b2[idx - O_B2];
    } else if (idx < O_BC1) {
        int j = idx - O_WC1; int m = j / 84; int r = j % 84; int i = r / STR; int f = r % STR;
        if (f < BAD) val = Wc1[m * (NBK * BAD) + i * BAD + f];
    } else if (idx < O_WC2) {
        int m = idx - O_BC1;
        if (m < CM) val = bc1[m];
    } else if (idx < O_BC2) {
        int j = idx - O_WC2; int o = j / 12, m = j % 12;
        if (m < CM) val = Wc2[o * CM + m];
    } else {
        int o = idx - O_BC2;
        if (o < 3) val = bc2[o];
    }
    ws[idx] = val;
}

// 2 threads/element, split by WAVE-pair (uniform control flow per wave):
//   waves 0,1 (role 0): conf MLP + bilinear numerators
//   waves 2,3 (role 1): linear terms + quadratic forms
// Exchange 21 fp32/elem via the At LDS region (free before a_tilde packing).
// Both roles redundantly compute softmax + a_tilde (cheap, fp32-exact).
// Phase 2: 6 MFMA row-tiles/wave, per-wave interleaved 16x40 P buffer
// (same-wave LDS round-trip, validated in R9 without barriers).
__global__ __launch_bounds__(256) void main_kernel(
    const float* __restrict__ states, const float* __restrict__ action,
    const int* __restrict__ block_id,
    const float* __restrict__ ws, float* __restrict__ out) {
    __shared__ __align__(16) unsigned short At[384 * 40];    // 30720 B
    __shared__ __align__(16) unsigned short Pb[4 * 16 * 40]; // 5120 B

    int t = threadIdx.x;
    int w = t >> 6, l = t & 63;
    int role = w >> 1;
    int eb = ((w & 1) << 6) + l;                 // 0..127
    long elem = (long)blockIdx.x * EPB + eb;

    const float* st = states + elem * (NBK * SS);
    const float* ac = action + elem * NA;
    const int* bid = block_id + elem * NBK;

    // ---- build ba[3][25] (both roles, all indices compile-time) ----
    float ba[NBK * BAD];
    #pragma unroll
    for (int i = 0; i < NBK; ++i) {
        const float4* s4 = (const float4*)(st + i * SS);
        #pragma unroll
        for (int v4 = 0; v4 < 4; ++v4) {
            float4 v = s4[v4];
            ba[i * BAD + v4 * 4 + 0] = v.x;
            ba[i * BAD + v4 * 4 + 1] = v.y;
            ba[i * BAD + v4 * 4 + 2] = v.z;
            ba[i * BAD + v4 * 4 + 3] = v.w;
        }
        bool sel = (bid[i] == 1);
        #pragma unroll
        for (int c = 0; c < NA; ++c)
            ba[i * BAD + SS + c] = sel ? ac[c] : -1.0f;
    }

    float* ex = (float*)At;                      // exchange: eb*25 + [0..20]

    if (role == 0) {
        // ---- confidence MLP -> out directly ----
        float hm[CM];
        #pragma unroll
        for (int m = 0; m < CM; ++m) {
            float s = ws[O_BC1 + m];
            #pragma unroll
            for (int i = 0; i < NBK; ++i)
                #pragma unroll
                for (int f = 0; f < BAD; ++f)
                    s += ws[O_WC1 + m * 84 + i * STR + f] * ba[i * BAD + f];
            hm[m] = fast_sigmoid(s);
        }
        float* op = out + elem * OUTD;
        #pragma unroll
        for (int o = 0; o < 3; ++o) {
            float s = ws[O_BC2 + o];
            #pragma unroll
            for (int m = 0; m < CM; ++m) s += ws[O_WC2 + o * 12 + m] * hm[m];
            op[48 + o] = fast_sigmoid(s);
        }
        // ---- bilinear numerators ----
        float num[NBK][NBK] = {{0.f,0.f,0.f},{0.f,0.f,0.f},{0.f,0.f,0.f}};
        #pragma unroll
        for (int e = 0; e < BAD; ++e) {
            float t0 = 0.f, t1 = 0.f, t2 = 0.f;
            #pragma unroll
            for (int f = 0; f < BAD; ++f) {
                float g = ws[O_GQK + e * STR + f];
                t0 += g * ba[0 * BAD + f];
                t1 += g * ba[1 * BAD + f];
                t2 += g * ba[2 * BAD + f];
            }
            #pragma unroll
            for (int i = 0; i < NBK; ++i) {
                float be = ba[i * BAD + e];
                num[i][0] += be * t0;
                num[i][1] += be * t1;
                num[i][2] += be * t2;
            }
        }
        #pragma unroll
        for (int i = 0; i < NBK; ++i)
            #pragma unroll
            for (int j = 0; j < NBK; ++j) ex[eb * 25 + i * 3 + j] = num[i][j];
    } else {
        // ---- linear score terms ----
        float s1[NBK], s2[NBK], dq[NBK], dk[NBK];
        #pragma unroll
        for (int p = 0; p < NBK; ++p) {
            float a1 = 0.f, a2 = 0.f, aq = 0.f, ak = 0.f;
            #pragma unroll
            for (int e = 0; e < BAD; ++e) {
                float b = ba[p * BAD + e];
                a1 += ws[O_V1 + e] * b;
                a2 += ws[O_V2 + e] * b;
                aq += ws[O_VQ + e] * b;
                ak += ws[O_VK + e] * b;
            }
            s1[p] = a1; s2[p] = a2; dq[p] = aq; dk[p] = ak;
        }
        float cq = ws[O_C + 1], ck = ws[O_C + 2];
        // ---- quadratic forms via scaled lower triangles ----
        float qn2[NBK] = {0.f, 0.f, 0.f}, kn2[NBK] = {0.f, 0.f, 0.f};
        #pragma unroll
        for (int e = 0; e < BAD; ++e) {
            float pq0 = 0.f, pq1 = 0.f, pq2 = 0.f;
            float pk0 = 0.f, pk1 = 0.f, pk2 = 0.f;
            #pragma unroll
            for (int f = 0; f <= e; ++f) {
                float gq = ws[O_GQQ + e * STR + f];
                float gk = ws[O_GKK + e * STR + f];
                float b0 = ba[0 * BAD + f], b1v = ba[1 * BAD + f], b2v = ba[2 * BAD + f];
                pq0 += gq * b0; pq1 += gq * b1v; pq2 += gq * b2v;
                pk0 += gk * b0; pk1 += gk * b1v; pk2 += gk * b2v;
            }
            qn2[0] += ba[0 * BAD + e] * pq0;
            qn2[1] += ba[1 * BAD + e] * pq1;
            qn2[2] += ba[2 * BAD + e] * pq2;
            kn2[0] += ba[0 * BAD + e] * pk0;
            kn2[1] += ba[1 * BAD + e] * pk1;
            kn2[2] += ba[2 * BAD + e] * pk2;
        }
        #pragma unroll
        for (int p = 0; p < NBK; ++p) {
            ex[eb * 25 + 9 + p]  = s1[p];
            ex[eb * 25 + 12 + p] = s2[p];
            ex[eb * 25 + 15 + p] = qn2[p] + 2.0f * dq[p] + cq;
            ex[eb * 25 + 18 + p] = kn2[p] + 2.0f * dk[p] + ck;
        }
    }
    __syncthreads();

    // ---- both roles: gather exchange, softmax, a_tilde ----
    float num[NBK][NBK], s1[NBK], s2[NBK], qn2[NBK], kn2[NBK];
    #pragma unroll
    for (int i = 0; i < NBK; ++i)
        #pragma unroll
        for (int j = 0; j < NBK; ++j) num[i][j] = ex[eb * 25 + i * 3 + j];
    #pragma unroll
    for (int p = 0; p < NBK; ++p) {
        s1[p]  = ex[eb * 25 + 9 + p];
        s2[p]  = ex[eb * 25 + 12 + p];
        qn2[p] = ex[eb * 25 + 15 + p];
        kn2[p] = ex[eb * 25 + 18 + p];
    }
    float c0 = ws[O_C + 0];

    float att[NBK][NBK];
    {
        float kn[NBK];
        #pragma unroll
        for (int j = 0; j < NBK; ++j) kn[j] = __builtin_amdgcn_sqrtf(fmaxf(kn2[j], 0.0f));
        #pragma unroll
        for (int i = 0; i < NBK; ++i) {
            float qn = __builtin_amdgcn_sqrtf(fmaxf(qn2[i], 0.0f));
            float dv[NBK];
            #pragma unroll
            for (int j = 0; j < NBK; ++j)
                dv[j] = (num[i][j] + s1[i] + s2[j] + c0) *
                        __builtin_amdgcn_rcpf(fmaxf(qn * kn[j], EPS));
            float mx = fmaxf(dv[0], fmaxf(dv[1], dv[2]));
            float e0 = __expf(dv[0] - mx);
            float e1 = __expf(dv[1] - mx);
            float e2 = __expf(dv[2] - mx);
            float inv = __builtin_amdgcn_rcpf(e0 + e1 + e2);
            att[i][0] = e0 * inv;
            att[i][1] = e1 * inv;
            att[i][2] = e2 * inv;
        }
    }

    // a_tilde in place
    #pragma unroll
    for (int e = 0; e < BAD; ++e) {
        float b0 = ba[0 * BAD + e], b1v = ba[1 * BAD + e], b2v = ba[2 * BAD + e];
        ba[0 * BAD + e] = att[0][0] * b0 + att[0][1] * b1v + att[0][2] * b2v;
        ba[1 * BAD + e] = att[1][0] * b0 + att[1][1] * b1v + att[1][2] * b2v;
        ba[2 * BAD + e] = att[2][0] * b0 + att[2][1] * b1v + att[2][2] * b2v;
    }
    __syncthreads();   // all exchange reads done before At pack overwrites

    // ---- pack a_tilde rows to At bf16 (role0: i=0,1; role1: i=2) ----
    {
        int i0 = (role == 0) ? 0 : 2;
        int i1 = (role == 0) ? 2 : 3;   // role0 packs {0,1}, role1 packs {2}
        for (int i = i0; i < i1; ++i) {
            int ii = (role == 0) ? i : 2;
            unsigned int* dst = (unsigned int*)&At[(eb * 3 + ii) * 40];
            #pragma unroll
            for (int pr = 0; pr < 12; ++pr)
                dst[pr] = (unsigned int)f2bf(ba[ii * BAD + 2 * pr]) |
                          ((unsigned int)f2bf(ba[ii * BAD + 2 * pr + 1]) << 16);
            dst[12] = (unsigned int)f2bf(ba[ii * BAD + 24]) | (0x3F80u << 16);
            dst[13] = 0u; dst[14] = 0u; dst[15] = 0u;
        }
    }
    __syncthreads();

    // ================= phase 2: MFMA (6 tiles/wave) =================
    int lane = l, m = l & 15, q = l >> 4;
    unsigned short* Pw = &Pb[w * 640];           // 16 x 40
    const short8* pkM = (const short8*)(ws + O_PKM);
    const short8* pkW2 = (const short8*)(ws + O_PKW2);
    float b2v = ws[O_B2 + m];
    long blockbase = (long)blockIdx.x * EPB;

    for (int tt = 0; tt < 6; ++tt) {
        int tile = w * 6 + tt;                   // rows tile*16 .. +15 (of 384)
        short8 af = *(const short8*)&At[(tile * 16 + m) * 40 + q * 8];
        floatx4 acc2 = {0.f, 0.f, 0.f, 0.f};
        #pragma unroll
        for (int kt = 0; kt < 4; ++kt) {
            floatx4 z = {0.f, 0.f, 0.f, 0.f};
            floatx4 a0 = __builtin_amdgcn_mfma_f32_16x16x32_bf16(af, pkM[(2 * kt) * 64 + lane], z, 0, 0, 0);
            floatx4 a1 = __builtin_amdgcn_mfma_f32_16x16x32_bf16(af, pkM[(2 * kt + 1) * 64 + lane], z, 0, 0, 0);
            #pragma unroll
            for (int r = 0; r < 4; ++r) {
                float v0 = fmaf(-2.0f, __builtin_amdgcn_rcpf(1.0f + __expf(a0[r])), 1.0f);
                float v1 = fmaf(-2.0f, __builtin_amdgcn_rcpf(1.0f + __expf(a1[r])), 1.0f);
                Pw[(q * 4 + r) * 40 + m] = f2bf(v0);
                Pw[(q * 4 + r) * 40 + 16 + m] = f2bf(v1);
            }
            short8 a2 = *(const short8*)&Pw[m * 40 + q * 8];
            acc2 = __builtin_amdgcn_mfma_f32_16x16x32_bf16(a2, pkW2[kt * 64 + lane], acc2, 0, 0, 0);
        }
        #pragma unroll
        for (int r = 0; r < 4; ++r) {
            int lrow = tile * 16 + q * 4 + r;    // 0..383
            int et = lrow / 3, i = lrow - et * 3;
            long ge = blockbase + et;
            float base = states[ge * 48 + i * 16 + m];
            out[ge * OUTD + i * 16 + m] = acc2[r] + base + b2v;
        }
    }
}

extern "C" void kernel_launch(void* const* d_in, const int* in_sizes, int n_in,
                              void* d_out, int out_size, void* d_ws, size_t ws_size,
                              hipStream_t stream) {
    const float* states = (const float*)d_in[0];
    const float* action = (const float*)d_in[1];
    const int* block_id = (const int*)d_in[2];
    const float* Wq = (const float*)d_in[3];
    const float* bq = (const float*)d_in[4];
    const float* Wk = (const float*)d_in[5];
    const float* bk = (const float*)d_in[6];
    const float* Wv = (const float*)d_in[7];
    const float* bv = (const float*)d_in[8];
    const float* W1 = (const float*)d_in[9];
    const float* b1 = (const float*)d_in[10];
    const float* W2 = (const float*)d_in[11];
    const float* b2 = (const float*)d_in[12];
    const float* Wc1 = (const float*)d_in[13];
    const float* bc1 = (const float*)d_in[14];
    const float* Wc2 = (const float*)d_in[15];
    const float* bc2 = (const float*)d_in[16];
    float* out = (float*)d_out;
    float* ws = (float*)d_ws;

    hipLaunchKernelGGL(prep_kernel, dim3((TOT_IDX + 255) / 256), dim3(256), 0, stream,
                       Wq, bq, Wk, bk, Wv, bv, W1, b1, W2, b2, Wc1, bc1, Wc2, bc2, ws);
    hipLaunchKernelGGL(main_kernel, dim3(BTOT / EPB), dim3(256), 0, stream,
                       states, action, block_id, ws, out);
}